// Round 9
// baseline (2467.057 us; speedup 1.0000x reference)
//
#include <hip/hip_runtime.h>

// Problem sizes (fixed)
#define NR 120000   // occupied voxels
#define CI 32
#define CO 64
#define KK 27

// async global->LDS, 16B per lane. LDS dest must be wave-uniform base + lane*16.
#define GLOAD_LDS16(g, l) __builtin_amdgcn_global_load_lds( \
    (const __attribute__((address_space(1))) unsigned int*)(g), \
    (__attribute__((address_space(3))) unsigned int*)(l), 16, 0, 0)

// ---------------------------------------------------------------------------
// K1: conv1 (32->64, 27 offsets) + classifier/mask + compaction.
// Unchanged working structure (DMA dbuf, one barrier/k). Adds: per-block
// strong-row bitmask (mwords -> mkbits) for K2's gather predication.
// ---------------------------------------------------------------------------
__global__ __launch_bounds__(256, 2)
void k_conv1(const float* __restrict__ xF, const float* __restrict__ gum,
             const int* __restrict__ nbr, const float* __restrict__ Wch,
             const float* __restrict__ bch, const float* __restrict__ Wcls,
             const float* __restrict__ bcls, const float* __restrict__ zbufX,
             float* __restrict__ x1m, int* __restrict__ sids,
             int* __restrict__ cnt, unsigned* __restrict__ mkbits,
             float* __restrict__ outp)
{
    __shared__ float gs[2 * 128 * CI];      // 32 KB
    __shared__ float Ws[2][CI * CO];        // 16 KB
    __shared__ int   sl[128];
    __shared__ unsigned mwords[4];
    __shared__ int   scnt, sbase;

    const int t    = threadIdx.x;
    const int dq   = t & 15;
    const int rq   = t >> 4;
    const int rq7  = rq & 7;
    const int dq4  = dq * 4;
    const int sr   = t >> 3;   // staging row within 32-row chunk
    const int sq   = t & 7;    // staging quad
    const int row0 = blockIdx.x * 128;

    if (t == 0) scnt = 0;
    if (t < 4) mwords[t] = 0u;

    // --- prologue: k=0 DMA, W[0]->LDS, prefetch k=1 ids and W[1] ---
    int jr[4];
#pragma unroll
    for (int pp = 0; pp < 4; ++pp) {
        int i = row0 + pp * 32 + sr;
        jr[pp] = (i < NR) ? nbr[i * KK] : NR;
    }
#pragma unroll
    for (int pp = 0; pp < 4; ++pp) {
        int r = pp * 32 + sr;
        const float* gsrc = (jr[pp] < NR) ? (xF + (size_t)jr[pp] * CI)
                                          : (zbufX + (r & 63) * CI);
        GLOAD_LDS16(gsrc + ((sq ^ (r & 7)) << 2), &gs[(pp * 256 + t) * 4]);
    }
    {
        const float4* Wk = (const float4*)Wch;
        float4 a0 = Wk[t], a1 = Wk[t + 256];
        float4* Wv = (float4*)&Ws[0][0];
        Wv[t] = a0; Wv[t + 256] = a1;
    }
#pragma unroll
    for (int pp = 0; pp < 4; ++pp) {
        int i = row0 + pp * 32 + sr;
        jr[pp] = (i < NR) ? nbr[i * KK + 1] : NR;
    }
    float4 wr0, wr1;
    {
        const float4* Wk = (const float4*)(Wch + CI * CO);
        wr0 = Wk[t]; wr1 = Wk[t + 256];
    }

    const float4 bq = ((const float4*)bch)[dq];
    float4 acc[8];
#pragma unroll
    for (int rp = 0; rp < 8; ++rp) acc[rp] = bq;

    float wcA[4], wcB[4];
#pragma unroll
    for (int c = 0; c < 4; ++c) {
        wcA[c] = Wcls[(dq4 + c) * 2];
        wcB[c] = Wcls[(dq4 + c) * 2 + 1];
    }
    const float b0 = bcls[0], b1 = bcls[1];

    int gso = 0, wp = 0;
    __syncthreads();   // gs buf0 + Ws[0] + mwords init ready

#pragma unroll 1
    for (int k = 0; k < KK; ++k) {
        if (k < KK - 1) {
#pragma unroll
            for (int pp = 0; pp < 4; ++pp) {
                int r = pp * 32 + sr;
                const float* gsrc = (jr[pp] < NR) ? (xF + (size_t)jr[pp] * CI)
                                                  : (zbufX + (r & 63) * CI);
                GLOAD_LDS16(gsrc + ((sq ^ (r & 7)) << 2),
                            &gs[(gso ^ (128 * CI)) + (pp * 256 + t) * 4]);
            }
            float4* Wv = (float4*)&Ws[wp ^ 1][0];
            Wv[t] = wr0; Wv[t + 256] = wr1;
        }
        if (k < KK - 2) {
#pragma unroll
            for (int pp = 0; pp < 4; ++pp) {
                int i = row0 + pp * 32 + sr;
                jr[pp] = (i < NR) ? nbr[i * KK + k + 2] : NR;
            }
            const float4* Wk = (const float4*)(Wch + (size_t)(k + 2) * CI * CO);
            wr0 = Wk[t]; wr1 = Wk[t + 256];
        }
        // compute k
        const float* gsb = &gs[gso];
        const float* wsb = &Ws[wp][0];
#pragma unroll
        for (int cq = 0; cq < CI / 4; ++cq) {
            float4 w0 = *(const float4*)&wsb[(cq * 4 + 0) * CO + dq4];
            float4 w1 = *(const float4*)&wsb[(cq * 4 + 1) * CO + dq4];
            float4 w2 = *(const float4*)&wsb[(cq * 4 + 2) * CO + dq4];
            float4 w3 = *(const float4*)&wsb[(cq * 4 + 3) * CO + dq4];
            const int cs = ((cq ^ rq7) << 2);
#pragma unroll
            for (int rp = 0; rp < 8; ++rp) {
                float4 g = *(const float4*)&gsb[(rp * 16 + rq) * CI + cs];
                acc[rp].x += g.x * w0.x + g.y * w1.x + g.z * w2.x + g.w * w3.x;
                acc[rp].y += g.x * w0.y + g.y * w1.y + g.z * w2.y + g.w * w3.y;
                acc[rp].z += g.x * w0.z + g.y * w1.z + g.z * w2.z + g.w * w3.z;
                acc[rp].w += g.x * w0.w + g.y * w1.w + g.z * w2.w + g.w * w3.w;
            }
        }
        __syncthreads();   // drains DMA + orders Ws write for next iter
        gso ^= (128 * CI); wp ^= 1;
    }

    // epilogue: classifier (16-lane shuffle reduce), mask, writes
#pragma unroll
    for (int rp = 0; rp < 8; ++rp) {
        float4 a = acc[rp];
        float p0 = a.x * wcA[0] + a.y * wcA[1] + a.z * wcA[2] + a.w * wcA[3];
        float p1 = a.x * wcB[0] + a.y * wcB[1] + a.z * wcB[2] + a.w * wcB[3];
#pragma unroll
        for (int off = 1; off < 16; off <<= 1) {
            p0 += __shfl_xor(p0, off, 64);
            p1 += __shfl_xor(p1, off, 64);
        }
        int i = row0 + rp * 16 + rq;
        if (i < NR) {
            float z0 = p0 + b0 + gum[2 * i];
            float z1 = p1 + b1 + gum[2 * i + 1];
            bool m = (z0 >= z1);   // argmax tie -> index 0 -> strong
            ((float4*)(outp + (size_t)i * CO))[dq] =
                make_float4(2.f * a.x, 2.f * a.y, 2.f * a.z, 2.f * a.w);
            float4 xm = m ? a : make_float4(0.f, 0.f, 0.f, 0.f);
            ((float4*)(x1m + (size_t)i * CO))[dq] = xm;
            if (dq == 0 && m) {
                int lr = rp * 16 + rq;
                atomicOr(&mwords[lr >> 5], 1u << (lr & 31));
                int pos = atomicAdd(&scnt, 1); sl[pos] = i;
            }
        }
    }
    __syncthreads();
    if (t < 4) mkbits[(row0 >> 5) + t] = mwords[t];
    if (t == 0) sbase = atomicAdd(cnt, scnt);
    __syncthreads();
    if (t < scnt) sids[sbase + t] = sl[t];
}

// ---------------------------------------------------------------------------
// K2: conv2 (64->64) over compacted strong rows. T14 register-staged pipeline,
// now with: 64 rows/block (2x active blocks, 33.5 KB LDS, 4 blocks/CU),
// halved register arrays, and bitmask-predicated gathers (weak/invalid
// neighbor -> register zero, NO load: ~50% of gather traffic vanishes).
// ---------------------------------------------------------------------------
__global__ __launch_bounds__(256, 4)
void k_conv2(const float* __restrict__ x1m, const int* __restrict__ nbr,
             const float* __restrict__ Wdw, const float* __restrict__ bdw,
             const int* __restrict__ sids, const int* __restrict__ cnt,
             const unsigned* __restrict__ mkbits, float* __restrict__ outp)
{
    const int nstrong = *cnt;
    const int row0 = blockIdx.x * 64;
    if (row0 >= nstrong) return;

    __shared__ float gs[64][68];    // 17.4 KB, stride 68 words -> conflict-free
    __shared__ float Ws[CO * CO];   // 16 KB

    const int t   = threadIdx.x;
    const int dq  = t & 15;
    const int rq  = t >> 4;
    const int dq4 = dq * 4;

    int ssid[4];
#pragma unroll
    for (int p = 0; p < 4; ++p) {
        int rr = row0 + p * 16 + rq;
        ssid[p] = (rr < nstrong) ? sids[rr] : -1;
    }

    int jn[4]; unsigned mw[4];
#pragma unroll
    for (int p = 0; p < 4; ++p)
        jn[p] = (ssid[p] >= 0) ? nbr[ssid[p] * KK] : NR;
#pragma unroll
    for (int p = 0; p < 4; ++p) mw[p] = mkbits[jn[p] >> 5];

    // prologue: k=0 tile -> regs (mask-predicated), W[0] -> regs, ids(k=1)
    float4 vbuf[4];
#pragma unroll
    for (int p = 0; p < 4; ++p) {
        bool s = (mw[p] >> (jn[p] & 31)) & 1u;
        vbuf[p] = s ? ((const float4*)(x1m + (size_t)jn[p] * CO))[dq]
                    : make_float4(0.f, 0.f, 0.f, 0.f);
    }
    float4 w0r, w1r, w2r, w3r;
    {
        const float4* Wk = (const float4*)Wdw;
        w0r = Wk[t]; w1r = Wk[t + 256]; w2r = Wk[t + 512]; w3r = Wk[t + 768];
    }
#pragma unroll
    for (int p = 0; p < 4; ++p)
        jn[p] = (ssid[p] >= 0) ? nbr[ssid[p] * KK + 1] : NR;
#pragma unroll
    for (int p = 0; p < 4; ++p) mw[p] = mkbits[jn[p] >> 5];

    float4 acc[4];
#pragma unroll
    for (int rp = 0; rp < 4; ++rp) acc[rp] = make_float4(0.f, 0.f, 0.f, 0.f);

#pragma unroll 1
    for (int k = 0; k < KK; ++k) {
        // commit staged regs -> LDS (loads issued one compute-phase ago)
#pragma unroll
        for (int p = 0; p < 4; ++p)
            *(float4*)&gs[p * 16 + rq][dq4] = vbuf[p];
        {
            float4* Wv = (float4*)Ws;
            Wv[t] = w0r; Wv[t + 256] = w1r; Wv[t + 512] = w2r; Wv[t + 768] = w3r;
        }
        __syncthreads();   // staging visible

        if (k < KK - 1) {
            // issue next tile's gathers (bitmask-predicated) + W prefetch
#pragma unroll
            for (int p = 0; p < 4; ++p) {
                bool s = (mw[p] >> (jn[p] & 31)) & 1u;
                vbuf[p] = s ? ((const float4*)(x1m + (size_t)jn[p] * CO))[dq]
                            : make_float4(0.f, 0.f, 0.f, 0.f);
            }
            const float4* Wk = (const float4*)(Wdw + (size_t)(k + 1) * CO * CO);
            w0r = Wk[t]; w1r = Wk[t + 256]; w2r = Wk[t + 512]; w3r = Wk[t + 768];
            if (k < KK - 2) {
#pragma unroll
                for (int p = 0; p < 4; ++p)
                    jn[p] = (ssid[p] >= 0) ? nbr[ssid[p] * KK + k + 2] : NR;
#pragma unroll
                for (int p = 0; p < 4; ++p) mw[p] = mkbits[jn[p] >> 5];
            }
        }

        // compute k
#pragma unroll
        for (int cq = 0; cq < CO / 4; ++cq) {
            float4 w0 = *(const float4*)&Ws[(cq * 4 + 0) * CO + dq4];
            float4 w1 = *(const float4*)&Ws[(cq * 4 + 1) * CO + dq4];
            float4 w2 = *(const float4*)&Ws[(cq * 4 + 2) * CO + dq4];
            float4 w3 = *(const float4*)&Ws[(cq * 4 + 3) * CO + dq4];
#pragma unroll
            for (int rp = 0; rp < 4; ++rp) {
                float4 g = *(const float4*)&gs[rp * 16 + rq][cq * 4];
                acc[rp].x += g.x * w0.x + g.y * w1.x + g.z * w2.x + g.w * w3.x;
                acc[rp].y += g.x * w0.y + g.y * w1.y + g.z * w2.y + g.w * w3.y;
                acc[rp].z += g.x * w0.z + g.y * w1.z + g.z * w2.z + g.w * w3.z;
                acc[rp].w += g.x * w0.w + g.y * w1.w + g.z * w2.w + g.w * w3.w;
            }
        }
        __syncthreads();   // all waves done reading gs/Ws before next commit
    }

    const float4 bq = ((const float4*)bdw)[dq];
#pragma unroll
    for (int rp = 0; rp < 4; ++rp) {
        int rr = row0 + rp * 16 + rq;
        if (rr < nstrong) {
            int sid = sids[rr];
            float4 xv = ((const float4*)(x1m + (size_t)sid * CO))[dq];
            float4 a = acc[rp];
            ((float4*)(outp + (size_t)sid * CO))[dq] =
                make_float4(a.x + bq.x + xv.x, a.y + bq.y + xv.y,
                            a.z + bq.z + xv.z, a.w + bq.w + xv.w);
        }
    }
}

// ---------------------------------------------------------------------------
extern "C" void kernel_launch(void* const* d_in, const int* in_sizes, int n_in,
                              void* d_out, int out_size, void* d_ws, size_t ws_size,
                              hipStream_t stream)
{
    const float* xF   = (const float*)d_in[0];
    const float* gum  = (const float*)d_in[1];
    const int*   nbr  = (const int*)d_in[2];
    const float* Wch  = (const float*)d_in[3];
    const float* bch  = (const float*)d_in[4];
    const float* Wcls = (const float*)d_in[5];
    const float* bcls = (const float*)d_in[6];
    const float* Wdw  = (const float*)d_in[7];
    const float* bdw  = (const float*)d_in[8];
    // d_in[9] = th (unused by the forward computation)

    float* outp = (float*)d_out;
    char*  ws   = (char*)d_ws;

    // ws layout (x1m FIRST -> 256B-aligned rows, no line straddle):
    //   [0, 30720000)            x1m  (N*64 f32)
    //   [30720000, 30728192)     zbufX (64 zero rows x 32 f32)
    //   [30728192, 30728196)     cnt
    //   [30728320, 30743360)     mkbits (3760 u32, incl. sentinel guard word)
    //   [30743360, 31223360)     sids (N i32)
    float*    x1m    = (float*)(ws);
    float*    zbufX  = (float*)(ws + 30720000);
    int*      cnt    = (int*)(ws + 30728192);
    unsigned* mkbits = (unsigned*)(ws + 30728320);
    int*      sids   = (int*)(ws + 30743360);

    // zero zbufX + cnt + mkbits in one shot
    hipMemsetAsync(ws + 30720000, 0, 30743360 - 30720000, stream);

    hipLaunchKernelGGL(k_conv1, dim3((NR + 127) / 128), dim3(256), 0, stream,
                       xF, gum, nbr, Wch, bch, Wcls, bcls, zbufX,
                       x1m, sids, cnt, mkbits, outp);
    hipLaunchKernelGGL(k_conv2, dim3((NR + 63) / 64), dim3(256), 0, stream,
                       x1m, nbr, Wdw, bdw, sids, cnt, mkbits, outp);
}

// Round 10
// 772.080 us; speedup vs baseline: 3.1953x; 3.1953x over previous
//
#include <hip/hip_runtime.h>

// Problem sizes (fixed)
#define NR 120000   // occupied voxels
#define CI 32
#define CO 64
#define KK 27

// async global->LDS, 16B per lane. LDS dest must be wave-uniform base + lane*16.
#define GLOAD_LDS16(g, l) __builtin_amdgcn_global_load_lds( \
    (const __attribute__((address_space(1))) unsigned int*)(g), \
    (__attribute__((address_space(3))) unsigned int*)(l), 16, 0, 0)

// ---------------------------------------------------------------------------
// K1: conv1 (32->64, 27 offsets) + classifier/mask + compaction.
// Proven structure (rounds 7/9): DMA dbuf gs + dbuf Ws, one barrier/k.
// Emits strong-row bitmask (mkbits) for K2's gather predication.
// ---------------------------------------------------------------------------
__global__ __launch_bounds__(256, 2)
void k_conv1(const float* __restrict__ xF, const float* __restrict__ gum,
             const int* __restrict__ nbr, const float* __restrict__ Wch,
             const float* __restrict__ bch, const float* __restrict__ Wcls,
             const float* __restrict__ bcls, const float* __restrict__ zbufX,
             float* __restrict__ x1m, int* __restrict__ sids,
             int* __restrict__ cnt, unsigned* __restrict__ mkbits,
             float* __restrict__ outp)
{
    __shared__ float gs[2 * 128 * CI];      // 32 KB
    __shared__ float Ws[2][CI * CO];        // 16 KB
    __shared__ int   sl[128];
    __shared__ unsigned mwords[4];
    __shared__ int   scnt, sbase;

    const int t    = threadIdx.x;
    const int dq   = t & 15;
    const int rq   = t >> 4;
    const int rq7  = rq & 7;
    const int dq4  = dq * 4;
    const int sr   = t >> 3;   // staging row within 32-row chunk
    const int sq   = t & 7;    // staging quad
    const int row0 = blockIdx.x * 128;

    if (t == 0) scnt = 0;
    if (t < 4) mwords[t] = 0u;

    // --- prologue: k=0 DMA, W[0]->LDS, prefetch k=1 ids and W[1] ---
    int jr[4];
#pragma unroll
    for (int pp = 0; pp < 4; ++pp) {
        int i = row0 + pp * 32 + sr;
        jr[pp] = (i < NR) ? nbr[i * KK] : NR;
    }
#pragma unroll
    for (int pp = 0; pp < 4; ++pp) {
        int r = pp * 32 + sr;
        const float* gsrc = (jr[pp] < NR) ? (xF + (size_t)jr[pp] * CI)
                                          : (zbufX + (r & 63) * CI);
        GLOAD_LDS16(gsrc + ((sq ^ (r & 7)) << 2), &gs[(pp * 256 + t) * 4]);
    }
    {
        const float4* Wk = (const float4*)Wch;
        float4 a0 = Wk[t], a1 = Wk[t + 256];
        float4* Wv = (float4*)&Ws[0][0];
        Wv[t] = a0; Wv[t + 256] = a1;
    }
#pragma unroll
    for (int pp = 0; pp < 4; ++pp) {
        int i = row0 + pp * 32 + sr;
        jr[pp] = (i < NR) ? nbr[i * KK + 1] : NR;
    }
    float4 wr0, wr1;
    {
        const float4* Wk = (const float4*)(Wch + CI * CO);
        wr0 = Wk[t]; wr1 = Wk[t + 256];
    }

    const float4 bq = ((const float4*)bch)[dq];
    float4 acc[8];
#pragma unroll
    for (int rp = 0; rp < 8; ++rp) acc[rp] = bq;

    float wcA[4], wcB[4];
#pragma unroll
    for (int c = 0; c < 4; ++c) {
        wcA[c] = Wcls[(dq4 + c) * 2];
        wcB[c] = Wcls[(dq4 + c) * 2 + 1];
    }
    const float b0 = bcls[0], b1 = bcls[1];

    int gso = 0, wp = 0;
    __syncthreads();   // gs buf0 + Ws[0] + mwords init ready

#pragma unroll 1
    for (int k = 0; k < KK; ++k) {
        if (k < KK - 1) {
#pragma unroll
            for (int pp = 0; pp < 4; ++pp) {
                int r = pp * 32 + sr;
                const float* gsrc = (jr[pp] < NR) ? (xF + (size_t)jr[pp] * CI)
                                                  : (zbufX + (r & 63) * CI);
                GLOAD_LDS16(gsrc + ((sq ^ (r & 7)) << 2),
                            &gs[(gso ^ (128 * CI)) + (pp * 256 + t) * 4]);
            }
            float4* Wv = (float4*)&Ws[wp ^ 1][0];
            Wv[t] = wr0; Wv[t + 256] = wr1;
        }
        if (k < KK - 2) {
#pragma unroll
            for (int pp = 0; pp < 4; ++pp) {
                int i = row0 + pp * 32 + sr;
                jr[pp] = (i < NR) ? nbr[i * KK + k + 2] : NR;
            }
            const float4* Wk = (const float4*)(Wch + (size_t)(k + 2) * CI * CO);
            wr0 = Wk[t]; wr1 = Wk[t + 256];
        }
        // compute k
        const float* gsb = &gs[gso];
        const float* wsb = &Ws[wp][0];
#pragma unroll
        for (int cq = 0; cq < CI / 4; ++cq) {
            float4 w0 = *(const float4*)&wsb[(cq * 4 + 0) * CO + dq4];
            float4 w1 = *(const float4*)&wsb[(cq * 4 + 1) * CO + dq4];
            float4 w2 = *(const float4*)&wsb[(cq * 4 + 2) * CO + dq4];
            float4 w3 = *(const float4*)&wsb[(cq * 4 + 3) * CO + dq4];
            const int cs = ((cq ^ rq7) << 2);
#pragma unroll
            for (int rp = 0; rp < 8; ++rp) {
                float4 g = *(const float4*)&gsb[(rp * 16 + rq) * CI + cs];
                acc[rp].x += g.x * w0.x + g.y * w1.x + g.z * w2.x + g.w * w3.x;
                acc[rp].y += g.x * w0.y + g.y * w1.y + g.z * w2.y + g.w * w3.y;
                acc[rp].z += g.x * w0.z + g.y * w1.z + g.z * w2.z + g.w * w3.z;
                acc[rp].w += g.x * w0.w + g.y * w1.w + g.z * w2.w + g.w * w3.w;
            }
        }
        __syncthreads();   // drains DMA + orders Ws write for next iter
        gso ^= (128 * CI); wp ^= 1;
    }

    // epilogue: classifier (16-lane shuffle reduce), mask, writes
#pragma unroll
    for (int rp = 0; rp < 8; ++rp) {
        float4 a = acc[rp];
        float p0 = a.x * wcA[0] + a.y * wcA[1] + a.z * wcA[2] + a.w * wcA[3];
        float p1 = a.x * wcB[0] + a.y * wcB[1] + a.z * wcB[2] + a.w * wcB[3];
#pragma unroll
        for (int off = 1; off < 16; off <<= 1) {
            p0 += __shfl_xor(p0, off, 64);
            p1 += __shfl_xor(p1, off, 64);
        }
        int i = row0 + rp * 16 + rq;
        if (i < NR) {
            float z0 = p0 + b0 + gum[2 * i];
            float z1 = p1 + b1 + gum[2 * i + 1];
            bool m = (z0 >= z1);   // argmax tie -> index 0 -> strong
            ((float4*)(outp + (size_t)i * CO))[dq] =
                make_float4(2.f * a.x, 2.f * a.y, 2.f * a.z, 2.f * a.w);
            float4 xm = m ? a : make_float4(0.f, 0.f, 0.f, 0.f);
            ((float4*)(x1m + (size_t)i * CO))[dq] = xm;
            if (dq == 0 && m) {
                int lr = rp * 16 + rq;
                atomicOr(&mwords[lr >> 5], 1u << (lr & 31));
                int pos = atomicAdd(&scnt, 1); sl[pos] = i;
            }
        }
    }
    __syncthreads();
    if (t < 4) mkbits[(row0 >> 5) + t] = mwords[t];
    if (t == 0) sbase = atomicAdd(cnt, scnt);
    __syncthreads();
    if (t < scnt) sids[sbase + t] = sl[t];
}

// ---------------------------------------------------------------------------
// K2: conv2 (64->64) over compacted strong rows — K1's DMA template cloned.
// 64 rows/block (938 active blocks). Per k: async global_load_lds DMA of the
// next tile into the other gs buffer (weak/invalid neighbors redirect to a
// SPREAD 64-row zero buffer -> no hot line, no 256B random zero loads),
// dbuf Ws via reg prefetch, ONE barrier per k. LDS 64 KB -> 2 blocks/CU.
// Staging: slot=p*256+t, r=p*16+(t>>4), q=t&15; swizzle q^(r&15) both sides.
// ---------------------------------------------------------------------------
__global__ __launch_bounds__(256, 2)
void k_conv2(const float* __restrict__ x1m, const int* __restrict__ nbr,
             const float* __restrict__ Wdw, const float* __restrict__ bdw,
             const int* __restrict__ sids, const int* __restrict__ cnt,
             const unsigned* __restrict__ mkbits, const float* __restrict__ zbuf1,
             float* __restrict__ outp)
{
    const int nstrong = *cnt;
    const int row0 = blockIdx.x * 64;
    if (row0 >= nstrong) return;

    __shared__ float gs[2][64 * CO];   // 32 KB
    __shared__ float Ws[2][CO * CO];   // 32 KB

    const int t   = threadIdx.x;
    const int dq  = t & 15;    // channel quad (compute) / staging quad sq
    const int rq  = t >> 4;    // row-in-group (compute & staging)
    const int dq4 = dq * 4;

    int ssid[4];
#pragma unroll
    for (int p = 0; p < 4; ++p) {
        int rr = row0 + p * 16 + rq;
        ssid[p] = (rr < nstrong) ? sids[rr] : -1;
    }

    // --- prologue: ids(k=0) + mask, DMA k=0, W0 -> Ws[0], ids(k=1), W1 regs ---
    int jn[4]; unsigned mw[4];
#pragma unroll
    for (int p = 0; p < 4; ++p)
        jn[p] = (ssid[p] >= 0) ? nbr[ssid[p] * KK] : NR;
#pragma unroll
    for (int p = 0; p < 4; ++p) mw[p] = mkbits[jn[p] >> 5];

#pragma unroll
    for (int p = 0; p < 4; ++p) {
        int r = p * 16 + rq;
        bool s = (mw[p] >> (jn[p] & 31)) & 1u;
        const float* gsrc = s ? (x1m + (size_t)jn[p] * CO) : (zbuf1 + r * CO);
        GLOAD_LDS16(gsrc + ((dq ^ rq) << 2), &gs[0][(p * 256 + t) * 4]);
    }
    float4 w0r, w1r, w2r, w3r;
    {
        const float4* Wk = (const float4*)Wdw;
        w0r = Wk[t]; w1r = Wk[t + 256]; w2r = Wk[t + 512]; w3r = Wk[t + 768];
        float4* Wv = (float4*)&Ws[0][0];
        Wv[t] = w0r; Wv[t + 256] = w1r; Wv[t + 512] = w2r; Wv[t + 768] = w3r;
    }
#pragma unroll
    for (int p = 0; p < 4; ++p)
        jn[p] = (ssid[p] >= 0) ? nbr[ssid[p] * KK + 1] : NR;
#pragma unroll
    for (int p = 0; p < 4; ++p) mw[p] = mkbits[jn[p] >> 5];
    {
        const float4* Wk = (const float4*)(Wdw + (size_t)CO * CO);
        w0r = Wk[t]; w1r = Wk[t + 256]; w2r = Wk[t + 512]; w3r = Wk[t + 768];
    }

    float4 acc[4];
#pragma unroll
    for (int rp = 0; rp < 4; ++rp) acc[rp] = make_float4(0.f, 0.f, 0.f, 0.f);

    int gso = 0, wp = 0;
    __syncthreads();   // gs[0] DMA + Ws[0] drained

#pragma unroll 1
    for (int k = 0; k < KK; ++k) {
        if (k < KK - 1) {
            // DMA next tile into other gs buffer (hides under compute)
#pragma unroll
            for (int p = 0; p < 4; ++p) {
                int r = p * 16 + rq;
                bool s = (mw[p] >> (jn[p] & 31)) & 1u;
                const float* gsrc = s ? (x1m + (size_t)jn[p] * CO)
                                      : (zbuf1 + r * CO);
                GLOAD_LDS16(gsrc + ((dq ^ rq) << 2),
                            &gs[gso ^ 1][(p * 256 + t) * 4]);
            }
            // write W(k+1) (prefetched last iter) into other Ws buffer
            float4* Wv = (float4*)&Ws[wp ^ 1][0];
            Wv[t] = w0r; Wv[t + 256] = w1r; Wv[t + 512] = w2r; Wv[t + 768] = w3r;
        }
        if (k < KK - 2) {
            // prefetch ids(k+2)+mask and W(k+2)
#pragma unroll
            for (int p = 0; p < 4; ++p)
                jn[p] = (ssid[p] >= 0) ? nbr[ssid[p] * KK + k + 2] : NR;
#pragma unroll
            for (int p = 0; p < 4; ++p) mw[p] = mkbits[jn[p] >> 5];
            const float4* Wk = (const float4*)(Wdw + (size_t)(k + 2) * CO * CO);
            w0r = Wk[t]; w1r = Wk[t + 256]; w2r = Wk[t + 512]; w3r = Wk[t + 768];
        }
        // compute k
        const float* gsb = &gs[gso][0];
        const float* wsb = &Ws[wp][0];
#pragma unroll
        for (int cq = 0; cq < CO / 4; ++cq) {
            float4 w0 = *(const float4*)&wsb[(cq * 4 + 0) * CO + dq4];
            float4 w1 = *(const float4*)&wsb[(cq * 4 + 1) * CO + dq4];
            float4 w2 = *(const float4*)&wsb[(cq * 4 + 2) * CO + dq4];
            float4 w3 = *(const float4*)&wsb[(cq * 4 + 3) * CO + dq4];
            const int cs = ((cq ^ rq) & 15) << 2;
#pragma unroll
            for (int rp = 0; rp < 4; ++rp) {
                float4 g = *(const float4*)&gsb[(rp * 16 + rq) * CO + cs];
                acc[rp].x += g.x * w0.x + g.y * w1.x + g.z * w2.x + g.w * w3.x;
                acc[rp].y += g.x * w0.y + g.y * w1.y + g.z * w2.y + g.w * w3.y;
                acc[rp].z += g.x * w0.z + g.y * w1.z + g.z * w2.z + g.w * w3.z;
                acc[rp].w += g.x * w0.w + g.y * w1.w + g.z * w2.w + g.w * w3.w;
            }
        }
        __syncthreads();   // drains DMA + orders Ws write for next iter
        gso ^= 1; wp ^= 1;
    }

    const float4 bq = ((const float4*)bdw)[dq];
#pragma unroll
    for (int rp = 0; rp < 4; ++rp) {
        int rr = row0 + rp * 16 + rq;
        if (rr < nstrong) {
            int sid = ssid[rp];
            float4 xv = ((const float4*)(x1m + (size_t)sid * CO))[dq];
            float4 a = acc[rp];
            ((float4*)(outp + (size_t)sid * CO))[dq] =
                make_float4(a.x + bq.x + xv.x, a.y + bq.y + xv.y,
                            a.z + bq.z + xv.z, a.w + bq.w + xv.w);
        }
    }
}

// ---------------------------------------------------------------------------
extern "C" void kernel_launch(void* const* d_in, const int* in_sizes, int n_in,
                              void* d_out, int out_size, void* d_ws, size_t ws_size,
                              hipStream_t stream)
{
    const float* xF   = (const float*)d_in[0];
    const float* gum  = (const float*)d_in[1];
    const int*   nbr  = (const int*)d_in[2];
    const float* Wch  = (const float*)d_in[3];
    const float* bch  = (const float*)d_in[4];
    const float* Wcls = (const float*)d_in[5];
    const float* bcls = (const float*)d_in[6];
    const float* Wdw  = (const float*)d_in[7];
    const float* bdw  = (const float*)d_in[8];
    // d_in[9] = th (unused by the forward computation)

    float* outp = (float*)d_out;
    char*  ws   = (char*)d_ws;

    // ws layout (x1m FIRST -> 256B-aligned rows):
    //   [0, 30720000)            x1m   (N*64 f32)
    //   [30720000, 30728192)     zbufX (64 zero rows x 32 f32, 8 KB)
    //   [30728192, 30744576)     zbuf1 (64 zero rows x 64 f32, 16 KB)
    //   [30744576, 30744580)     cnt
    //   [30744704, 30759744)     mkbits (3760 u32, sentinel word included)
    //   [30759744, 31239744)     sids (N i32)
    float*    x1m    = (float*)(ws);
    float*    zbufX  = (float*)(ws + 30720000);
    float*    zbuf1  = (float*)(ws + 30728192);
    int*      cnt    = (int*)(ws + 30744576);
    unsigned* mkbits = (unsigned*)(ws + 30744704);
    int*      sids   = (int*)(ws + 30759744);

    // zero zbufX + zbuf1 + cnt + mkbits in one shot
    hipMemsetAsync(ws + 30720000, 0, 30759744 - 30720000, stream);

    hipLaunchKernelGGL(k_conv1, dim3((NR + 127) / 128), dim3(256), 0, stream,
                       xF, gum, nbr, Wch, bch, Wcls, bcls, zbufX,
                       x1m, sids, cnt, mkbits, outp);
    hipLaunchKernelGGL(k_conv2, dim3((NR + 63) / 64), dim3(256), 0, stream,
                       x1m, nbr, Wdw, bdw, sids, cnt, mkbits, zbuf1, outp);
}